// Round 2
// baseline (2202.477 us; speedup 1.0000x reference)
//
#include <hip/hip_runtime.h>
#include <cstdint>
#include <cstddef>

#define NN 20000
#define NE 320000

struct KB10 { const float* p[10]; };
struct PP { const float* yo0; const float* yo1; const float* yi0; const float* yi1;
            float* po0; float* po1; float* pi0; float* pi1; };

// ---------------- init / graph ----------------

__global__ void k_zero(uint32_t* p, int n){
    int i = blockIdx.x*256 + threadIdx.x;
    if(i < n) p[i] = 0u;
}

__global__ void k_degree(const int* __restrict__ ei, int* degout, int* degin){
    int e = blockIdx.x*256 + threadIdx.x;
    if(e < NE){
        atomicAdd(&degout[ei[e]], 1);
        atomicAdd(&degin[ei[NE+e]], 1);
    }
}

__global__ void k_scan(const int* __restrict__ degin, int* __restrict__ coloff,
                       float* __restrict__ invdegin){
    __shared__ int part[1024];
    int t = threadIdx.x;
    int base = t*20;
    int s = 0;
    for(int k=0;k<20;k++){ int i = base+k; if(i < NN) s += degin[i]; }
    part[t] = s;
    __syncthreads();
    for(int off=1; off<1024; off<<=1){
        int v = (t>=off) ? part[t-off] : 0;
        __syncthreads();
        part[t] += v;
        __syncthreads();
    }
    int run = (t>0) ? part[t-1] : 0;   // exclusive prefix
    for(int k=0;k<20;k++){
        int i = base+k;
        if(i < NN){
            int d = degin[i];
            coloff[i] = run;
            run += d;
            invdegin[i] = (d>0) ? (1.0f/(float)d) : 0.0f;
        }
    }
    if(t==1023) coloff[NN] = part[1023];
}

__global__ void k_csr(const int* __restrict__ ei, const int* __restrict__ degout,
                      const int* __restrict__ coloff, int* cnt,
                      int* __restrict__ esrc, float* __restrict__ enormo){
    int e = blockIdx.x*256 + threadIdx.x;
    if(e < NE){
        int r = ei[e], c = ei[NE+e];
        int pos = coloff[c] + atomicAdd(&cnt[c], 1);
        esrc[pos] = r;
        enormo[pos] = 1.0f/(float)degout[r];
    }
}

// ---------------- CNN embedding ----------------
// y1 layout: [node][32 ch][32 pos] (31 valid + 1 zero pad)

__global__ void k_conv1(const float* __restrict__ x, const float* __restrict__ w1,
                        const float* __restrict__ b1, float* __restrict__ y1){
    __shared__ float w[320];
    __shared__ float bb[32];
    int t = threadIdx.x;
    for(int i=t;i<320;i+=256) w[i] = w1[i];
    if(t < 32) bb[t] = b1[t];
    __syncthreads();
    int gid = blockIdx.x*256 + t;
    if(gid >= NN*31) return;
    int node = gid/31, p = gid - node*31;
    const float* xr = x + node*100 + 3*p;
    float xv[10];
    #pragma unroll
    for(int k=0;k<10;k++) xv[k] = xr[k];
    float* yo = y1 + (size_t)node*1024 + p;
    #pragma unroll
    for(int c=0;c<32;c++){
        float a = bb[c];
        #pragma unroll
        for(int k=0;k<10;k++) a = fmaf(w[c*10+k], xv[k], a);
        yo[c*32] = fmaxf(a, 0.0f);
    }
    if(p == 0){
        #pragma unroll
        for(int c=0;c<32;c++) y1[(size_t)node*1024 + c*32 + 31] = 0.0f;
    }
}

template<int SLOTS, int PPC>
__global__ void k_chanstats(const float* __restrict__ y, float* __restrict__ sq){
    int tid = blockIdx.x*blockDim.x + threadIdx.x;
    int slot = tid & (SLOTS-1);
    int node0 = tid / SLOTS;
    int nstride = (gridDim.x*blockDim.x) / SLOTS;
    int c = slot / PPC;
    float s = 0.f, q = 0.f;
    for(int n=node0; n<NN; n+=nstride){
        float v = y[(size_t)n*SLOTS + slot];
        s += v; q = fmaf(v, v, q);
    }
    #pragma unroll
    for(int m=PPC>>1; m>0; m>>=1){
        s += __shfl_xor(s, m);
        q += __shfl_xor(q, m);
    }
    if((threadIdx.x & (PPC-1)) == 0){
        atomicAdd(&sq[c], s);
        atomicAdd(&sq[32+c], q);
    }
}

__global__ void k_bnfin(const float* __restrict__ sq, const float* __restrict__ gamma,
                        const float* __restrict__ beta, float* __restrict__ scsh,
                        float inv_count){
    int c = threadIdx.x;
    if(c < 32){
        float m = sq[c]*inv_count;
        float v = sq[32+c]*inv_count - m*m;
        float sc = gamma[c]*rsqrtf(v + 1e-5f);
        scsh[c] = sc;
        scsh[32+c] = beta[c] - m*sc;
    }
}

// one block per node; w LDS transposed [ck][c2] stride 33 (conflict-free)
// writes PRE-BN conv2 output (relu applied) to X
__global__ void __launch_bounds__(256) k_conv2(const float* __restrict__ y1,
                        const float* __restrict__ w2, const float* __restrict__ b2,
                        const float* __restrict__ scsh1, float* __restrict__ X){
    __shared__ float w[10560];   // [c*10+k]*33 + c2
    __shared__ float h[1024];    // [c][p] stride 32
    int t = threadIdx.x;
    for(int i=t;i<10240;i+=256){
        int c2 = i/320, ck = i - c2*320;
        w[ck*33 + c2] = w2[i];
    }
    int node = blockIdx.x;
    for(int i=t;i<1024;i+=256){
        int c = i>>5;
        h[i] = fmaf(scsh1[c], y1[(size_t)node*1024 + i], scsh1[32+c]);
    }
    __syncthreads();
    int c2 = t>>3, p2 = t&7;
    float a = b2[c2];
    #pragma unroll
    for(int c=0;c<32;c++){
        #pragma unroll
        for(int k=0;k<10;k++)
            a = fmaf(w[(c*10+k)*33 + c2], h[c*32 + 3*p2 + k], a);
    }
    X[(size_t)node*256 + t] = fmaxf(a, 0.f);
}

__global__ void k_bnapply(float* __restrict__ X, const float* __restrict__ scsh){
    int gid = blockIdx.x*256 + threadIdx.x;   // 20000*256 exact
    int c = (gid & 255) >> 3;
    X[gid] = fmaf(scsh[c], X[gid], scsh[32+c]);
}

// ---------------- effective weights ----------------
// W flat [2,3,512,256]; term: 0:W00+W10-W02-W12 1:W01 2:W11 3:2*W02 4:2*W12

__device__ __forceinline__ float weff_val(const float* W, int term, size_t base){
    const size_t S = 512*256;
    if(term==0)      return W[0*S+base] + W[3*S+base] - W[2*S+base] - W[5*S+base];
    else if(term==1) return W[1*S+base];
    else if(term==2) return W[4*S+base];
    else if(term==3) return 2.0f*W[2*S+base];
    else             return 2.0f*W[5*S+base];
}

// weffzr: [2560 rows][512 cols] = 10 kb-blocks of 256 rows; cols: 0:256 z, 256:512 r
__global__ void k_weff_zr(const float* __restrict__ Wz, const float* __restrict__ Wr,
                          float* __restrict__ We){
    int gid = blockIdx.x*256 + threadIdx.x;
    if(gid >= 2560*512) return;
    int r = gid >> 9, cf = gid & 511;
    const float* W = (cf < 256) ? Wz : Wr;
    int j = cf & 255;
    int kb = r >> 8, rr = r & 255;
    size_t base = (size_t)((kb & 1)*256 + rr)*256 + j;
    We[gid] = weff_val(W, kb>>1, base);
}

__global__ void k_weff_h(const float* __restrict__ Wh, float* __restrict__ We){
    int gid = blockIdx.x*256 + threadIdx.x;
    if(gid >= 2560*256) return;
    int r = gid >> 8, j = gid & 255;
    int kb = r >> 8, rr = r & 255;
    size_t base = (size_t)((kb & 1)*256 + rr)*256 + j;
    We[gid] = weff_val(Wh, kb>>1, base);
}

// ---------------- propagation (gather-only via CSR) ----------------
// po[i] = sum_e enormo[e]*Yo[src];  pi[i] = invdeg_in[i]*sum_e Yi[src]

template<int NB, bool SAME>
__global__ void __launch_bounds__(256) k_prop(PP a,
        const int* __restrict__ coloff, const int* __restrict__ esrc,
        const float* __restrict__ enormo, const float* __restrict__ invdegin){
    int node = blockIdx.x*4 + (threadIdx.x>>6);
    if(node >= NN) return;
    int lane = threadIdx.x & 63;
    int s = coloff[node], e = coloff[node+1];
    float ao[NB][4], ai[NB][4];
    #pragma unroll
    for(int b=0;b<NB;b++){
        #pragma unroll
        for(int q=0;q<4;q++){ ao[b][q]=0.f; ai[b][q]=0.f; }
    }
    const float* yo[2] = {a.yo0, a.yo1};
    const float* yi[2] = {a.yi0, a.yi1};
    for(int j=s;j<e;j++){
        int src = esrc[j];
        float w = enormo[j];
        size_t off = (size_t)src*256 + lane*4;
        #pragma unroll
        for(int b=0;b<NB;b++){
            float4 vo = *(const float4*)(yo[b] + off);
            float4 vi;
            if(SAME) vi = vo; else vi = *(const float4*)(yi[b] + off);
            ao[b][0] = fmaf(w, vo.x, ao[b][0]); ao[b][1] = fmaf(w, vo.y, ao[b][1]);
            ao[b][2] = fmaf(w, vo.z, ao[b][2]); ao[b][3] = fmaf(w, vo.w, ao[b][3]);
            ai[b][0] += vi.x; ai[b][1] += vi.y; ai[b][2] += vi.z; ai[b][3] += vi.w;
        }
    }
    float wi = invdegin[node];
    float* po[2] = {a.po0, a.po1};
    float* pi[2] = {a.pi0, a.pi1};
    size_t oo = (size_t)node*256 + lane*4;
    #pragma unroll
    for(int b=0;b<NB;b++){
        float4 o; o.x=ao[b][0]; o.y=ao[b][1]; o.z=ao[b][2]; o.w=ao[b][3];
        float4 q; q.x=wi*ai[b][0]; q.y=wi*ai[b][1]; q.z=wi*ai[b][2]; q.w=wi*ai[b][3];
        *(float4*)(po[b] + oo) = o;
        *(float4*)(pi[b] + oo) = q;
    }
}

// ---------------- block-descriptor GEMM + fused GRU epilogue ----------------
// C[20000 x nc] = sum_kb A_kb[20000 x 256 (ld=256)] * W[kb*256.., nc]
// MODE 0 (nc=512): cols<256 -> Z=sigmoid(+bz); cols>=256 -> RH=sigmoid(+br)*h0
// MODE 1 (nc=256): out = relu(z*h0 + (1-z)*tanh(+bh))

template<int MODE>
__global__ void __launch_bounds__(256) k_gemm(KB10 blocks, const float* __restrict__ W,
        int nc, const float* __restrict__ bias0, const float* __restrict__ bias1,
        const float* __restrict__ h0, const float* __restrict__ Zin,
        float* __restrict__ out0, float* __restrict__ out1){
    __shared__ float As[16][128];
    __shared__ float Bs[16][128];
    int t = threadIdx.x;
    int tx = t & 15, ty = t >> 4;
    int row0 = blockIdx.y * 128;
    int col0 = blockIdx.x * 128;
    float acc[8][8];
    #pragma unroll
    for(int r=0;r<8;r++){
        #pragma unroll
        for(int c=0;c<8;c++) acc[r][c] = 0.f;
    }
    for(int kb=0; kb<10; kb++){
        const float* Ap = blocks.p[kb];
        const float* Wp = W + (size_t)(kb*256)*nc + col0;
        for(int kt=0; kt<256; kt+=16){
            #pragma unroll
            for(int i=0;i<2;i++){
                int f = t + i*256;
                int m = f >> 2, kq = f & 3;
                int gr = row0 + m; gr = (gr < NN) ? gr : (NN-1);
                float4 v = *(const float4*)(Ap + (size_t)gr*256 + kt + kq*4);
                As[kq*4+0][m]=v.x; As[kq*4+1][m]=v.y; As[kq*4+2][m]=v.z; As[kq*4+3][m]=v.w;
            }
            #pragma unroll
            for(int i=0;i<2;i++){
                int f = t + i*256;
                int kk = f >> 5, cc = (f & 31)*4;
                *(float4*)&Bs[kk][cc] = *(const float4*)(Wp + (size_t)(kt+kk)*nc + cc);
            }
            __syncthreads();
            #pragma unroll
            for(int k=0;k<16;k++){
                float4 a0 = *(const float4*)&As[k][ty*4];
                float4 a1 = *(const float4*)&As[k][64+ty*4];
                float4 b0 = *(const float4*)&Bs[k][tx*4];
                float4 b1 = *(const float4*)&Bs[k][64+tx*4];
                float av[8] = {a0.x,a0.y,a0.z,a0.w,a1.x,a1.y,a1.z,a1.w};
                float bv[8] = {b0.x,b0.y,b0.z,b0.w,b1.x,b1.y,b1.z,b1.w};
                #pragma unroll
                for(int r=0;r<8;r++){
                    #pragma unroll
                    for(int c=0;c<8;c++)
                        acc[r][c] = fmaf(av[r], bv[c], acc[r][c]);
                }
            }
            __syncthreads();
        }
    }
    #pragma unroll
    for(int r=0;r<8;r++){
        int m = (r<4) ? (ty*4+r) : (64 + ty*4 + (r-4));
        int gr = row0 + m;
        if(gr < NN){
            #pragma unroll
            for(int half=0; half<2; half++){
                #pragma unroll
                for(int c=0;c<4;c++){
                    int j = col0 + half*64 + tx*4 + c;
                    float a = acc[r][half*4+c];
                    if(MODE == 0){
                        if(j < 256){
                            float zv = 1.0f/(1.0f + expf(-(a + bias0[j])));
                            out0[(size_t)gr*256 + j] = zv;
                        }else{
                            int jj = j - 256;
                            float rv = 1.0f/(1.0f + expf(-(a + bias1[jj])));
                            out1[(size_t)gr*256 + jj] = rv * h0[(size_t)gr*256 + jj];
                        }
                    }else{
                        float z = Zin[(size_t)gr*256 + j];
                        float ht = tanhf(a + bias0[j]);
                        float H = z*h0[(size_t)gr*256 + j] + (1.0f - z)*ht;
                        out0[(size_t)gr*256 + j] = fmaxf(H, 0.0f);
                    }
                }
            }
        }
    }
}

// ---------------- host ----------------

extern "C" void kernel_launch(void* const* d_in, const int* in_sizes, int n_in,
                              void* d_out, int out_size, void* d_ws, size_t ws_size,
                              hipStream_t stream){
    const float* x   = (const float*)d_in[0];
    const int*   ei  = (const int*)  d_in[1];
    const float* h0  = (const float*)d_in[2];
    const float* w1  = (const float*)d_in[3];
    const float* b1  = (const float*)d_in[4];
    const float* g1  = (const float*)d_in[5];
    const float* be1 = (const float*)d_in[6];
    const float* w2  = (const float*)d_in[7];
    const float* b2  = (const float*)d_in[8];
    const float* g2  = (const float*)d_in[9];
    const float* be2 = (const float*)d_in[10];
    const float* Wz  = (const float*)d_in[11];
    const float* bz  = (const float*)d_in[12];
    const float* Wr  = (const float*)d_in[13];
    const float* br  = (const float*)d_in[14];
    const float* Wh  = (const float*)d_in[15];
    const float* bh  = (const float*)d_in[16];
    float* out = (float*)d_out;
    float* wsf = (float*)d_ws;
    (void)in_sizes; (void)n_in; (void)out_size;

    // word (4B) offsets — total 59,026,688 words = 236,106,752 B
    const size_t O_DEGO=0, O_DEGI=20000, O_CNT=40000, O_BN=60000;      // zero: 60256 words
    const size_t O_COLOFF=60288, O_ESRC=80384, O_ENORMO=400384, O_INVDEG=720384;
    const size_t O_WEFFZR=740608, O_WEFFH=2051328;
    const size_t O_X=2706688;
    const size_t O_T1OX=7826688, O_T1IX=12946688, O_P2OX=18066688, O_P2IX=23186688;
    const size_t O_HS0=28306688, O_HS1=33426688, O_HS2=38546688, O_HS3=43666688;
    const size_t O_Z=48786688, O_RH=53906688;
    const size_t WS_NEED_BYTES = (size_t)59026688 * 4;
    if(ws_size < WS_NEED_BYTES) return;   // clean signal instead of OOB crash

    int* degout = (int*)(wsf + O_DEGO);
    int* degin  = (int*)(wsf + O_DEGI);
    int* cnt    = (int*)(wsf + O_CNT);
    float* bn   = wsf + O_BN;
    int* coloff = (int*)(wsf + O_COLOFF);
    int* esrc   = (int*)(wsf + O_ESRC);
    float* enormo = wsf + O_ENORMO;
    float* invdeg = wsf + O_INVDEG;
    float* weffzr = wsf + O_WEFFZR;
    float* weffh  = wsf + O_WEFFH;
    float* X    = wsf + O_X;
    float* T1oX = wsf + O_T1OX;
    float* T1iX = wsf + O_T1IX;
    float* P2oX = wsf + O_P2OX;
    float* P2iX = wsf + O_P2IX;
    float* HS0  = wsf + O_HS0;   // T1oH, later Q1o
    float* HS1  = wsf + O_HS1;   // T1iH, later Q1i
    float* HS2  = wsf + O_HS2;   // P2oH, later Q2o
    float* HS3  = wsf + O_HS3;   // P2iH, later Q2i
    float* Z    = wsf + O_Z;
    float* RH   = wsf + O_RH;
    float* y1   = wsf + O_HS0;   // 20,480,000 words: exactly HS0..HS3 (dead before props)

    // graph CSR
    k_zero<<<236,256,0,stream>>>((uint32_t*)(wsf + O_DEGO), 60256);
    k_degree<<<1250,256,0,stream>>>(ei, degout, degin);
    k_scan<<<1,1024,0,stream>>>(degin, coloff, invdeg);
    k_csr<<<1250,256,0,stream>>>(ei, degout, coloff, cnt, esrc, enormo);

    // CNN embedding
    k_conv1<<<2422,256,0,stream>>>(x, w1, b1, y1);
    k_chanstats<1024,32><<<256,256,0,stream>>>(y1, bn+0);
    k_bnfin<<<1,32,0,stream>>>(bn+0, g1, be1, bn+64, 1.0f/620000.0f);
    k_conv2<<<20000,256,0,stream>>>(y1, w2, b2, bn+64, X);
    k_chanstats<256,8><<<64,256,0,stream>>>(X, bn+128);
    k_bnfin<<<1,32,0,stream>>>(bn+128, g2, be2, bn+192, 1.0f/160000.0f);
    k_bnapply<<<20000,256,0,stream>>>(X, bn+192);

    // effective weights
    k_weff_zr<<<5120,256,0,stream>>>(Wz, Wr, weffzr);
    k_weff_h<<<2560,256,0,stream>>>(Wh, weffh);

    // hop1: props of X and H0 (one edge pass)
    PP p1; p1.yo0=X; p1.yo1=h0; p1.yi0=X; p1.yi1=h0;
    p1.po0=T1oX; p1.po1=HS0; p1.pi0=T1iX; p1.pi1=HS1;
    k_prop<2,true><<<5000,256,0,stream>>>(p1, coloff, esrc, enormo, invdeg);

    // hop2
    PP p2; p2.yo0=T1oX; p2.yo1=HS0; p2.yi0=T1iX; p2.yi1=HS1;
    p2.po0=P2oX; p2.po1=HS2; p2.pi0=P2iX; p2.pi1=HS3;
    k_prop<2,false><<<5000,256,0,stream>>>(p2, coloff, esrc, enormo, invdeg);

    // Z,R GEMM (fused sigmoid, RH = sigmoid(r)*h0)
    KB10 bzr = {{ X, h0, T1oX, HS0, T1iX, HS1, P2oX, HS2, P2iX, HS3 }};
    k_gemm<0><<<dim3(4,157),256,0,stream>>>(bzr, weffzr, 512, bz, br, h0, nullptr, Z, RH);

    // props of RH (overwrites dead H-side buffers)
    PP q1; q1.yo0=RH; q1.yo1=nullptr; q1.yi0=RH; q1.yi1=nullptr;
    q1.po0=HS0; q1.po1=nullptr; q1.pi0=HS1; q1.pi1=nullptr;
    k_prop<1,true><<<5000,256,0,stream>>>(q1, coloff, esrc, enormo, invdeg);
    PP q2; q2.yo0=HS0; q2.yo1=nullptr; q2.yi0=HS1; q2.yi1=nullptr;
    q2.po0=HS2; q2.po1=nullptr; q2.pi0=HS3; q2.pi1=nullptr;
    k_prop<1,false><<<5000,256,0,stream>>>(q2, coloff, esrc, enormo, invdeg);

    // H~ GEMM (fused tanh + gate + relu -> out)
    KB10 bhh = {{ X, RH, T1oX, HS0, T1iX, HS1, P2oX, HS2, P2iX, HS3 }};
    k_gemm<1><<<dim3(2,157),256,0,stream>>>(bhh, weffh, 256, bh, nullptr, h0, Z, out, nullptr);
}

// Round 3
// 975.413 us; speedup vs baseline: 2.2580x; 2.2580x over previous
//
#include <hip/hip_runtime.h>
#include <cstdint>
#include <cstddef>

#define NN 20000
#define NE 320000

typedef float f32x4 __attribute__((ext_vector_type(4)));
typedef short s16x8 __attribute__((ext_vector_type(8)));

struct KB10 { const unsigned short* p[10]; };
struct PPB { const unsigned short* yo0; const unsigned short* yo1;
             const unsigned short* yi0; const unsigned short* yi1;
             unsigned short* po0; unsigned short* po1;
             unsigned short* pi0; unsigned short* pi1; };

__device__ __forceinline__ unsigned short f2bf(float x){
    unsigned u = __float_as_uint(x);
    unsigned r = (u + 0x7fffu + ((u >> 16) & 1u)) >> 16;
    return (unsigned short)r;
}
__device__ __forceinline__ float bf2f(unsigned short s){
    return __uint_as_float(((unsigned)s) << 16);
}

__device__ __forceinline__ void gl16(const void* g, void* l){
    __builtin_amdgcn_global_load_lds((const __attribute__((address_space(1))) unsigned int*)g,
                                     (__attribute__((address_space(3))) unsigned int*)l, 16, 0, 0);
}

// ---------------- init / graph ----------------

__global__ void k_zero(uint32_t* p, int n){
    int i = blockIdx.x*256 + threadIdx.x;
    if(i < n) p[i] = 0u;
}

__global__ void k_degree(const int* __restrict__ ei, int* degout, int* degin){
    int e = blockIdx.x*256 + threadIdx.x;
    if(e < NE){
        atomicAdd(&degout[ei[e]], 1);
        atomicAdd(&degin[ei[NE+e]], 1);
    }
}

__global__ void k_scan(const int* __restrict__ degin, int* __restrict__ coloff,
                       float* __restrict__ invdegin){
    __shared__ int part[1024];
    int t = threadIdx.x;
    int base = t*20;
    int s = 0;
    for(int k=0;k<20;k++){ int i = base+k; if(i < NN) s += degin[i]; }
    part[t] = s;
    __syncthreads();
    for(int off=1; off<1024; off<<=1){
        int v = (t>=off) ? part[t-off] : 0;
        __syncthreads();
        part[t] += v;
        __syncthreads();
    }
    int run = (t>0) ? part[t-1] : 0;
    for(int k=0;k<20;k++){
        int i = base+k;
        if(i < NN){
            int d = degin[i];
            coloff[i] = run;
            run += d;
            invdegin[i] = (d>0) ? (1.0f/(float)d) : 0.0f;
        }
    }
    if(t==1023) coloff[NN] = part[1023];
}

__global__ void k_csr(const int* __restrict__ ei, const int* __restrict__ degout,
                      const int* __restrict__ coloff, int* cnt,
                      int* __restrict__ esrc, float* __restrict__ enormo){
    int e = blockIdx.x*256 + threadIdx.x;
    if(e < NE){
        int r = ei[e], c = ei[NE+e];
        int pos = coloff[c] + atomicAdd(&cnt[c], 1);
        esrc[pos] = r;
        enormo[pos] = 1.0f/(float)degout[r];
    }
}

// ---------------- CNN embedding ----------------

__global__ void k_conv1(const float* __restrict__ x, const float* __restrict__ w1,
                        const float* __restrict__ b1, float* __restrict__ y1){
    __shared__ float w[320];
    __shared__ float bb[32];
    int t = threadIdx.x;
    for(int i=t;i<320;i+=256) w[i] = w1[i];
    if(t < 32) bb[t] = b1[t];
    __syncthreads();
    int gid = blockIdx.x*256 + t;
    if(gid >= NN*31) return;
    int node = gid/31, p = gid - node*31;
    const float* xr = x + node*100 + 3*p;
    float xv[10];
    #pragma unroll
    for(int k=0;k<10;k++) xv[k] = xr[k];
    float* yo = y1 + (size_t)node*1024 + p;
    #pragma unroll
    for(int c=0;c<32;c++){
        float a = bb[c];
        #pragma unroll
        for(int k=0;k<10;k++) a = fmaf(w[c*10+k], xv[k], a);
        yo[c*32] = fmaxf(a, 0.0f);
    }
    if(p == 0){
        #pragma unroll
        for(int c=0;c<32;c++) y1[(size_t)node*1024 + c*32 + 31] = 0.0f;
    }
}

template<int SLOTS, int PPC>
__global__ void k_chanstats(const float* __restrict__ y, float* __restrict__ sq){
    int tid = blockIdx.x*blockDim.x + threadIdx.x;
    int slot = tid & (SLOTS-1);
    int node0 = tid / SLOTS;
    int nstride = (gridDim.x*blockDim.x) / SLOTS;
    int c = slot / PPC;
    float s = 0.f, q = 0.f;
    for(int n=node0; n<NN; n+=nstride){
        float v = y[(size_t)n*SLOTS + slot];
        s += v; q = fmaf(v, v, q);
    }
    #pragma unroll
    for(int m=PPC>>1; m>0; m>>=1){
        s += __shfl_xor(s, m);
        q += __shfl_xor(q, m);
    }
    if((threadIdx.x & (PPC-1)) == 0){
        atomicAdd(&sq[c], s);
        atomicAdd(&sq[32+c], q);
    }
}

__global__ void k_bnfin(const float* __restrict__ sq, const float* __restrict__ gamma,
                        const float* __restrict__ beta, float* __restrict__ scsh,
                        float inv_count){
    int c = threadIdx.x;
    if(c < 32){
        float m = sq[c]*inv_count;
        float v = sq[32+c]*inv_count - m*m;
        float sc = gamma[c]*rsqrtf(v + 1e-5f);
        scsh[c] = sc;
        scsh[32+c] = beta[c] - m*sc;
    }
}

__global__ void __launch_bounds__(256) k_conv2(const float* __restrict__ y1,
                        const float* __restrict__ w2, const float* __restrict__ b2,
                        const float* __restrict__ scsh1, float* __restrict__ Xf){
    __shared__ float w[10560];
    __shared__ float h[1024];
    int t = threadIdx.x;
    for(int i=t;i<10240;i+=256){
        int c2 = i/320, ck = i - c2*320;
        w[ck*33 + c2] = w2[i];
    }
    int node = blockIdx.x;
    for(int i=t;i<1024;i+=256){
        int c = i>>5;
        h[i] = fmaf(scsh1[c], y1[(size_t)node*1024 + i], scsh1[32+c]);
    }
    __syncthreads();
    int c2 = t>>3, p2 = t&7;
    float a = b2[c2];
    #pragma unroll
    for(int c=0;c<32;c++){
        #pragma unroll
        for(int k=0;k<10;k++)
            a = fmaf(w[(c*10+k)*33 + c2], h[c*32 + 3*p2 + k], a);
    }
    Xf[(size_t)node*256 + t] = fmaxf(a, 0.f);
}

__global__ void k_bnapply_bf(const float* __restrict__ Xf, const float* __restrict__ scsh,
                             unsigned short* __restrict__ Xb){
    int gid = blockIdx.x*256 + threadIdx.x;
    int c = (gid & 255) >> 3;
    Xb[gid] = f2bf(fmaf(scsh[c], Xf[gid], scsh[32+c]));
}

__global__ void k_tobf16(const float* __restrict__ a, unsigned short* __restrict__ b){
    int gid = blockIdx.x*256 + threadIdx.x;
    b[gid] = f2bf(a[gid]);
}

// ---------------- effective weights (transposed, bf16) ----------------
// term: 0:W00+W10-W02-W12 1:W01 2:W11 3:2*W02 4:2*W12

__device__ __forceinline__ float weff_val(const float* W, int term, size_t base){
    const size_t S = 512*256;
    if(term==0)      return W[0*S+base] + W[3*S+base] - W[2*S+base] - W[5*S+base];
    else if(term==1) return W[1*S+base];
    else if(term==2) return W[4*S+base];
    else if(term==3) return 2.0f*W[2*S+base];
    else             return 2.0f*W[5*S+base];
}

// Wt layout: [col][K=2560] bf16, K index = kb*256 + rr
__global__ void k_weff_zr_t(const float* __restrict__ Wz, const float* __restrict__ Wr,
                            unsigned short* __restrict__ Wt){
    int k = blockIdx.x*256 + threadIdx.x;
    int col = blockIdx.y;
    const float* W = (col < 256) ? Wz : Wr;
    int j = col & 255;
    int kb = k >> 8, rr = k & 255;
    size_t base = (size_t)((kb & 1)*256 + rr)*256 + j;
    Wt[(size_t)col*2560 + k] = f2bf(weff_val(W, kb>>1, base));
}

__global__ void k_weff_h_t(const float* __restrict__ Wh, unsigned short* __restrict__ Wt){
    int k = blockIdx.x*256 + threadIdx.x;
    int col = blockIdx.y;
    int kb = k >> 8, rr = k & 255;
    size_t base = (size_t)((kb & 1)*256 + rr)*256 + col;
    Wt[(size_t)col*2560 + k] = f2bf(weff_val(Wh, kb>>1, base));
}

// ---------------- propagation (bf16 gather via CSR) ----------------

template<int NB, bool SAME>
__global__ void __launch_bounds__(256) k_prop(PPB a,
        const int* __restrict__ coloff, const int* __restrict__ esrc,
        const float* __restrict__ enormo, const float* __restrict__ invdegin){
    int node = blockIdx.x*4 + (threadIdx.x>>6);
    if(node >= NN) return;
    int lane = threadIdx.x & 63;
    int s = coloff[node], e = coloff[node+1];
    float ao[NB][4], ai[NB][4];
    #pragma unroll
    for(int b=0;b<NB;b++){
        #pragma unroll
        for(int q=0;q<4;q++){ ao[b][q]=0.f; ai[b][q]=0.f; }
    }
    const unsigned short* yo[2] = {a.yo0, a.yo1};
    const unsigned short* yi[2] = {a.yi0, a.yi1};
    for(int j=s;j<e;j++){
        int src = esrc[j];
        float w = enormo[j];
        size_t off = (size_t)src*256 + lane*4;
        #pragma unroll
        for(int b=0;b<NB;b++){
            uint2 uo = *(const uint2*)(yo[b] + off);
            float fo0 = __uint_as_float(uo.x << 16), fo1 = __uint_as_float(uo.x & 0xffff0000u);
            float fo2 = __uint_as_float(uo.y << 16), fo3 = __uint_as_float(uo.y & 0xffff0000u);
            float fi0, fi1, fi2, fi3;
            if(SAME){ fi0=fo0; fi1=fo1; fi2=fo2; fi3=fo3; }
            else{
                uint2 ui = *(const uint2*)(yi[b] + off);
                fi0 = __uint_as_float(ui.x << 16); fi1 = __uint_as_float(ui.x & 0xffff0000u);
                fi2 = __uint_as_float(ui.y << 16); fi3 = __uint_as_float(ui.y & 0xffff0000u);
            }
            ao[b][0] = fmaf(w, fo0, ao[b][0]); ao[b][1] = fmaf(w, fo1, ao[b][1]);
            ao[b][2] = fmaf(w, fo2, ao[b][2]); ao[b][3] = fmaf(w, fo3, ao[b][3]);
            ai[b][0] += fi0; ai[b][1] += fi1; ai[b][2] += fi2; ai[b][3] += fi3;
        }
    }
    float wi = invdegin[node];
    unsigned short* po[2] = {a.po0, a.po1};
    unsigned short* pi[2] = {a.pi0, a.pi1};
    size_t oo = (size_t)node*256 + lane*4;
    #pragma unroll
    for(int b=0;b<NB;b++){
        unsigned po0 = ((unsigned)f2bf(ao[b][1])<<16) | f2bf(ao[b][0]);
        unsigned po1 = ((unsigned)f2bf(ao[b][3])<<16) | f2bf(ao[b][2]);
        unsigned pi0 = ((unsigned)f2bf(wi*ai[b][1])<<16) | f2bf(wi*ai[b][0]);
        unsigned pi1 = ((unsigned)f2bf(wi*ai[b][3])<<16) | f2bf(wi*ai[b][2]);
        uint2 o; o.x = po0; o.y = po1;
        uint2 q; q.x = pi0; q.y = pi1;
        *(uint2*)(po[b] + oo) = o;
        *(uint2*)(pi[b] + oo) = q;
    }
}

// ---------------- bf16 MFMA GEMM + fused GRU epilogue ----------------
// C[20000 x nc] = sum_kb A_kb[20000 x 256] * Wt[col][kb*256+k]
// MODE 0 (nc=512): j<256 -> Z=sigmoid(+bz) f32; j>=256 -> RH=bf16(sigmoid(+br)*h0)
// MODE 1 (nc=256): out = relu(z*h0 + (1-z)*tanh(+bh)) f32

template<int MODE>
__global__ void __launch_bounds__(256) k_gemm(KB10 blocks, const unsigned short* __restrict__ Wt,
        const float* __restrict__ bias0, const float* __restrict__ bias1,
        const float* __restrict__ h0, const float* __restrict__ Zin,
        float* __restrict__ out0, unsigned short* __restrict__ out1){
    __shared__ unsigned short As[4096];   // 128 rows x 32 k, 16B chunks: chunk=row*4+slot
    __shared__ unsigned short Bs[4096];   // 128 cols x 32 k
    int t = threadIdx.x;
    int wid = t >> 6, lane = t & 63;
    int l15 = lane & 15, kg = lane >> 4;
    int row0 = blockIdx.y * 128;
    int col0 = blockIdx.x * 128;
    int rowbase = (wid >> 1) * 64, colbase = (wid & 1) * 64;
    int swz = (l15 >> 1) & 3;             // (row>>1)&3 == (l15>>1)&3 for all frags
    f32x4 acc[4][4] = {};

    // staging decode (same for both passes per tile)
    int c0 = t, c1 = t + 256;
    int sr0 = c0 >> 2, sg0 = (c0 & 3) ^ ((sr0 >> 1) & 3);
    int sr1 = c1 >> 2, sg1 = (c1 & 3) ^ ((sr1 >> 1) & 3);
    int gra0 = row0 + sr0; gra0 = (gra0 < NN) ? gra0 : NN-1;
    int gra1 = row0 + sr1; gra1 = (gra1 < NN) ? gra1 : NN-1;

    for(int kb=0; kb<10; kb++){
        const unsigned short* Ap = blocks.p[kb];
        const unsigned short* Wp = Wt + (size_t)kb*256;
        for(int kt=0; kt<256; kt+=32){
            gl16(Ap + (size_t)gra0*256 + kt + sg0*8, As + c0*8);
            gl16(Ap + (size_t)gra1*256 + kt + sg1*8, As + c1*8);
            gl16(Wp + (size_t)(col0+sr0)*2560 + kt + sg0*8, Bs + c0*8);
            gl16(Wp + (size_t)(col0+sr1)*2560 + kt + sg1*8, Bs + c1*8);
            __syncthreads();
            s16x8 af[4], bf[4];
            #pragma unroll
            for(int i=0;i<4;i++){
                int row = rowbase + i*16 + l15;
                af[i] = *(const s16x8*)&As[(row*4 + (kg ^ swz))*8];
                int col = colbase + i*16 + l15;
                bf[i] = *(const s16x8*)&Bs[(col*4 + (kg ^ swz))*8];
            }
            #pragma unroll
            for(int mi=0;mi<4;mi++){
                #pragma unroll
                for(int ni=0;ni<4;ni++){
                    acc[mi][ni] = __builtin_amdgcn_mfma_f32_16x16x32_bf16(
                        af[mi], bf[ni], acc[mi][ni], 0, 0, 0);
                }
            }
            __syncthreads();
        }
    }

    #pragma unroll
    for(int mi=0;mi<4;mi++){
        int gr0 = row0 + rowbase + mi*16 + kg*4;
        #pragma unroll
        for(int ni=0;ni<4;ni++){
            int j = col0 + colbase + ni*16 + l15;
            #pragma unroll
            for(int r=0;r<4;r++){
                int gr = gr0 + r;
                if(gr < NN){
                    float a = acc[mi][ni][r];
                    if(MODE == 0){
                        if(j < 256){
                            out0[(size_t)gr*256 + j] = 1.0f/(1.0f + expf(-(a + bias0[j])));
                        }else{
                            int jj = j - 256;
                            float rv = 1.0f/(1.0f + expf(-(a + bias1[jj])));
                            out1[(size_t)gr*256 + jj] = f2bf(rv * h0[(size_t)gr*256 + jj]);
                        }
                    }else{
                        float z = Zin[(size_t)gr*256 + j];
                        float ht = tanhf(a + bias0[j]);
                        float H = z*h0[(size_t)gr*256 + j] + (1.0f - z)*ht;
                        out0[(size_t)gr*256 + j] = fmaxf(H, 0.0f);
                    }
                }
            }
        }
    }
}

// ---------------- host ----------------

extern "C" void kernel_launch(void* const* d_in, const int* in_sizes, int n_in,
                              void* d_out, int out_size, void* d_ws, size_t ws_size,
                              hipStream_t stream){
    const float* x   = (const float*)d_in[0];
    const int*   ei  = (const int*)  d_in[1];
    const float* h0  = (const float*)d_in[2];
    const float* w1  = (const float*)d_in[3];
    const float* b1  = (const float*)d_in[4];
    const float* g1  = (const float*)d_in[5];
    const float* be1 = (const float*)d_in[6];
    const float* w2  = (const float*)d_in[7];
    const float* b2  = (const float*)d_in[8];
    const float* g2  = (const float*)d_in[9];
    const float* be2 = (const float*)d_in[10];
    const float* Wz  = (const float*)d_in[11];
    const float* bz  = (const float*)d_in[12];
    const float* Wr  = (const float*)d_in[13];
    const float* br  = (const float*)d_in[14];
    const float* Wh  = (const float*)d_in[15];
    const float* bh  = (const float*)d_in[16];
    float* out = (float*)d_out;
    float* wsf = (float*)d_ws;
    (void)in_sizes; (void)n_in; (void)out_size;

    // word (4B) offsets
    const size_t O_DEGO=0, O_DEGI=20000, O_CNT=40000, O_BN=60000;      // zero: 60256
    const size_t O_COLOFF=60288, O_ESRC=80384, O_ENORMO=400384, O_INVDEG=720384;
    const size_t O_WTZR=740480, O_WTH=1395840;                         // bf16 (x2 elems/word)
    const size_t O_XF=1723520;
    const size_t O_XB=6843520, O_H0B=9403520;
    const size_t O_T1OX=11963520, O_T1IX=14523520, O_P2OX=17083520, O_P2IX=19643520;
    const size_t O_HS0=22203520, O_HS1=24763520, O_HS2=27323520, O_HS3=29883520;
    const size_t O_RH=32443520, O_Z=35003520;
    const size_t WS_NEED_BYTES = (size_t)40123520 * 4;                 // ~160.5 MB
    if(ws_size < WS_NEED_BYTES) return;

    int* degout = (int*)(wsf + O_DEGO);
    int* degin  = (int*)(wsf + O_DEGI);
    int* cnt    = (int*)(wsf + O_CNT);
    float* bn   = wsf + O_BN;
    int* coloff = (int*)(wsf + O_COLOFF);
    int* esrc   = (int*)(wsf + O_ESRC);
    float* enormo = wsf + O_ENORMO;
    float* invdeg = wsf + O_INVDEG;
    unsigned short* Wtzr = (unsigned short*)(wsf + O_WTZR);
    unsigned short* Wth  = (unsigned short*)(wsf + O_WTH);
    float* Xf = wsf + O_XF;
    unsigned short* Xb   = (unsigned short*)(wsf + O_XB);
    unsigned short* h0b  = (unsigned short*)(wsf + O_H0B);
    unsigned short* T1oX = (unsigned short*)(wsf + O_T1OX);
    unsigned short* T1iX = (unsigned short*)(wsf + O_T1IX);
    unsigned short* P2oX = (unsigned short*)(wsf + O_P2OX);
    unsigned short* P2iX = (unsigned short*)(wsf + O_P2IX);
    unsigned short* HS0  = (unsigned short*)(wsf + O_HS0);
    unsigned short* HS1  = (unsigned short*)(wsf + O_HS1);
    unsigned short* HS2  = (unsigned short*)(wsf + O_HS2);
    unsigned short* HS3  = (unsigned short*)(wsf + O_HS3);
    unsigned short* RH   = (unsigned short*)(wsf + O_RH);
    float* Z = wsf + O_Z;
    float* y1 = wsf + O_T1OX;   // 20.48M words fits T1OX..Z span (dead during CNN)

    // graph CSR
    k_zero<<<236,256,0,stream>>>((uint32_t*)(wsf + O_DEGO), 60256);
    k_degree<<<1250,256,0,stream>>>(ei, degout, degin);
    k_scan<<<1,1024,0,stream>>>(degin, coloff, invdeg);
    k_csr<<<1250,256,0,stream>>>(ei, degout, coloff, cnt, esrc, enormo);

    // CNN embedding
    k_conv1<<<2422,256,0,stream>>>(x, w1, b1, y1);
    k_chanstats<1024,32><<<256,256,0,stream>>>(y1, bn+0);
    k_bnfin<<<1,32,0,stream>>>(bn+0, g1, be1, bn+64, 1.0f/620000.0f);
    k_conv2<<<20000,256,0,stream>>>(y1, w2, b2, bn+64, Xf);
    k_chanstats<256,8><<<64,256,0,stream>>>(Xf, bn+128);
    k_bnfin<<<1,32,0,stream>>>(bn+128, g2, be2, bn+192, 1.0f/160000.0f);
    k_bnapply_bf<<<20000,256,0,stream>>>(Xf, bn+192, Xb);
    k_tobf16<<<20000,256,0,stream>>>(h0, h0b);

    // effective weights (transposed bf16)
    k_weff_zr_t<<<dim3(10,512),256,0,stream>>>(Wz, Wr, Wtzr);
    k_weff_h_t<<<dim3(10,256),256,0,stream>>>(Wh, Wth);

    // hop1: props of X and H0
    PPB p1; p1.yo0=Xb; p1.yo1=h0b; p1.yi0=Xb; p1.yi1=h0b;
    p1.po0=T1oX; p1.po1=HS0; p1.pi0=T1iX; p1.pi1=HS1;
    k_prop<2,true><<<5000,256,0,stream>>>(p1, coloff, esrc, enormo, invdeg);

    // hop2
    PPB p2; p2.yo0=T1oX; p2.yo1=HS0; p2.yi0=T1iX; p2.yi1=HS1;
    p2.po0=P2oX; p2.po1=HS2; p2.pi0=P2iX; p2.pi1=HS3;
    k_prop<2,false><<<5000,256,0,stream>>>(p2, coloff, esrc, enormo, invdeg);

    // Z,R GEMM (fused sigmoid; RH = bf16(sigmoid(r)*h0))
    KB10 bzr = {{ Xb, h0b, T1oX, HS0, T1iX, HS1, P2oX, HS2, P2iX, HS3 }};
    k_gemm<0><<<dim3(4,157),256,0,stream>>>(bzr, Wtzr, bz, br, h0, nullptr, Z, RH);

    // props of RH (reuse dead H-side buffers)
    PPB q1; q1.yo0=RH; q1.yo1=nullptr; q1.yi0=RH; q1.yi1=nullptr;
    q1.po0=HS0; q1.po1=nullptr; q1.pi0=HS1; q1.pi1=nullptr;
    k_prop<1,true><<<5000,256,0,stream>>>(q1, coloff, esrc, enormo, invdeg);
    PPB q2; q2.yo0=HS0; q2.yo1=nullptr; q2.yi0=HS1; q2.yi1=nullptr;
    q2.po0=HS2; q2.po1=nullptr; q2.pi0=HS3; q2.pi1=nullptr;
    k_prop<1,false><<<5000,256,0,stream>>>(q2, coloff, esrc, enormo, invdeg);

    // H~ GEMM (fused tanh + gate + relu -> out)
    KB10 bhh = {{ Xb, RH, T1oX, HS0, T1iX, HS1, P2oX, HS2, P2iX, HS3 }};
    k_gemm<1><<<dim3(2,157),256,0,stream>>>(bhh, Wth, bh, nullptr, h0, Z, out, nullptr);
}

// Round 4
// 797.935 us; speedup vs baseline: 2.7602x; 1.2224x over previous
//
#include <hip/hip_runtime.h>
#include <cstdint>
#include <cstddef>

#define NN 20000
#define NE 320000

typedef float f32x4 __attribute__((ext_vector_type(4)));
typedef short s16x8 __attribute__((ext_vector_type(8)));

struct KB10 { const unsigned short* p[10]; };
struct PPB { const unsigned short* yo0; const unsigned short* yo1;
             const unsigned short* yi0; const unsigned short* yi1;
             unsigned short* po0; unsigned short* po1;
             unsigned short* pi0; unsigned short* pi1; };

__device__ __forceinline__ unsigned short f2bf(float x){
    unsigned u = __float_as_uint(x);
    unsigned r = (u + 0x7fffu + ((u >> 16) & 1u)) >> 16;
    return (unsigned short)r;
}
__device__ __forceinline__ float bf2f(unsigned short s){
    return __uint_as_float(((unsigned)s) << 16);
}

__device__ __forceinline__ void gl16(const void* g, void* l){
    __builtin_amdgcn_global_load_lds((const __attribute__((address_space(1))) unsigned int*)g,
                                     (__attribute__((address_space(3))) unsigned int*)l, 16, 0, 0);
}

// ---------------- init / graph ----------------

__global__ void k_zero(uint32_t* p, int n){
    int i = blockIdx.x*256 + threadIdx.x;
    if(i < n) p[i] = 0u;
}

__global__ void k_degree(const int* __restrict__ ei, int* degout, int* degin){
    int e = blockIdx.x*256 + threadIdx.x;
    if(e < NE){
        atomicAdd(&degout[ei[e]], 1);
        atomicAdd(&degin[ei[NE+e]], 1);
    }
}

__global__ void k_scan(const int* __restrict__ degin, int* __restrict__ coloff,
                       float* __restrict__ invdegin){
    __shared__ int part[1024];
    int t = threadIdx.x;
    int base = t*20;
    int s = 0;
    for(int k=0;k<20;k++){ int i = base+k; if(i < NN) s += degin[i]; }
    part[t] = s;
    __syncthreads();
    for(int off=1; off<1024; off<<=1){
        int v = (t>=off) ? part[t-off] : 0;
        __syncthreads();
        part[t] += v;
        __syncthreads();
    }
    int run = (t>0) ? part[t-1] : 0;
    for(int k=0;k<20;k++){
        int i = base+k;
        if(i < NN){
            int d = degin[i];
            coloff[i] = run;
            run += d;
            invdegin[i] = (d>0) ? (1.0f/(float)d) : 0.0f;
        }
    }
    if(t==1023) coloff[NN] = part[1023];
}

__global__ void k_csr(const int* __restrict__ ei, const int* __restrict__ degout,
                      const int* __restrict__ coloff, int* cnt,
                      int* __restrict__ esrc, float* __restrict__ enormo){
    int e = blockIdx.x*256 + threadIdx.x;
    if(e < NE){
        int r = ei[e], c = ei[NE+e];
        int pos = coloff[c] + atomicAdd(&cnt[c], 1);
        esrc[pos] = r;
        enormo[pos] = 1.0f/(float)degout[r];
    }
}

// ---------------- CNN embedding ----------------
// y1b layout: [node][32 ch][32 pos] bf16 (31 valid + 1 zero pad)

__global__ void k_conv1(const float* __restrict__ x, const float* __restrict__ w1,
                        const float* __restrict__ b1, unsigned short* __restrict__ y1b){
    __shared__ float w[320];
    __shared__ float bb[32];
    int t = threadIdx.x;
    for(int i=t;i<320;i+=256) w[i] = w1[i];
    if(t < 32) bb[t] = b1[t];
    __syncthreads();
    int gid = blockIdx.x*256 + t;
    if(gid >= NN*31) return;
    int node = gid/31, p = gid - node*31;
    const float* xr = x + node*100 + 3*p;
    float xv[10];
    #pragma unroll
    for(int k=0;k<10;k++) xv[k] = xr[k];
    unsigned short* yo = y1b + (size_t)node*1024 + p;
    #pragma unroll
    for(int c=0;c<32;c++){
        float a = bb[c];
        #pragma unroll
        for(int k=0;k<10;k++) a = fmaf(w[c*10+k], xv[k], a);
        yo[c*32] = f2bf(fmaxf(a, 0.0f));
    }
    if(p == 0){
        #pragma unroll
        for(int c=0;c<32;c++) y1b[(size_t)node*1024 + c*32 + 31] = 0;
    }
}

template<int SLOTS, int PPC>
__global__ void k_chanstats_bf(const unsigned short* __restrict__ y, float* __restrict__ sq){
    int tid = blockIdx.x*blockDim.x + threadIdx.x;
    int slot = tid & (SLOTS-1);
    int node0 = tid / SLOTS;
    int nstride = (gridDim.x*blockDim.x) / SLOTS;
    int c = slot / PPC;
    float s = 0.f, q = 0.f;
    for(int n=node0; n<NN; n+=nstride){
        float v = bf2f(y[(size_t)n*SLOTS + slot]);
        s += v; q = fmaf(v, v, q);
    }
    #pragma unroll
    for(int m=PPC>>1; m>0; m>>=1){
        s += __shfl_xor(s, m);
        q += __shfl_xor(q, m);
    }
    if((threadIdx.x & (PPC-1)) == 0){
        atomicAdd(&sq[c], s);
        atomicAdd(&sq[32+c], q);
    }
}

__global__ void k_bnfin(const float* __restrict__ sq, const float* __restrict__ gamma,
                        const float* __restrict__ beta, float* __restrict__ scsh,
                        float inv_count){
    int c = threadIdx.x;
    if(c < 32){
        float m = sq[c]*inv_count;
        float v = sq[32+c]*inv_count - m*m;
        float sc = gamma[c]*rsqrtf(v + 1e-5f);
        scsh[c] = sc;
        scsh[32+c] = beta[c] - m*sc;
    }
}

// conv2 v2: 8 nodes/block, thread=(node_local, c2), register-blocked.
// w LDS [ck][c2] (conflict-free), h LDS [nl][1040] f32 with BN1 applied.
__global__ void __launch_bounds__(256) k_conv2(const unsigned short* __restrict__ y1b,
                        const float* __restrict__ w2, const float* __restrict__ b2,
                        const float* __restrict__ scsh1, unsigned short* __restrict__ Xpre){
    __shared__ float wlds[10240];   // [c*10+k]*32 + c2
    __shared__ float hlds[8*1040];  // [nl]*1040 + c*32 + p
    int t = threadIdx.x;
    int node0 = blockIdx.x*8;
    #pragma unroll
    for(int j=0;j<40;j++){
        int idx = j*256 + t;
        int ck = idx>>5, c2 = idx&31;
        wlds[ck*32 + c2] = w2[c2*320 + ck];
    }
    #pragma unroll
    for(int j=0;j<32;j++){
        int idx = j*256 + t;
        int nl = idx>>10, i = idx&1023;
        int c = i>>5;
        hlds[nl*1040 + i] = fmaf(scsh1[c], bf2f(y1b[(size_t)(node0+nl)*1024 + i]), scsh1[32+c]);
    }
    __syncthreads();
    int nl = t>>5, c2 = t&31;
    int hbase = nl*1040;
    float acc[8];
    float b = b2[c2];
    #pragma unroll
    for(int p=0;p<8;p++) acc[p] = b;
    for(int c=0;c<32;c++){
        float wr[10];
        #pragma unroll
        for(int k=0;k<10;k++) wr[k] = wlds[(c*10+k)*32 + c2];
        float hv[32];
        #pragma unroll
        for(int q=0;q<8;q++){
            float4 v = *(const float4*)&hlds[hbase + c*32 + q*4];
            hv[q*4+0]=v.x; hv[q*4+1]=v.y; hv[q*4+2]=v.z; hv[q*4+3]=v.w;
        }
        #pragma unroll
        for(int p=0;p<8;p++){
            #pragma unroll
            for(int k=0;k<10;k++)
                acc[p] = fmaf(wr[k], hv[3*p+k], acc[p]);
        }
    }
    uint4 pk;
    pk.x = ((unsigned)f2bf(fmaxf(acc[1],0.f))<<16) | f2bf(fmaxf(acc[0],0.f));
    pk.y = ((unsigned)f2bf(fmaxf(acc[3],0.f))<<16) | f2bf(fmaxf(acc[2],0.f));
    pk.z = ((unsigned)f2bf(fmaxf(acc[5],0.f))<<16) | f2bf(fmaxf(acc[4],0.f));
    pk.w = ((unsigned)f2bf(fmaxf(acc[7],0.f))<<16) | f2bf(fmaxf(acc[6],0.f));
    *(uint4*)&Xpre[(size_t)(node0+nl)*256 + c2*8] = pk;
}

__global__ void k_bnapply_bf(const unsigned short* __restrict__ Xpre,
                             const float* __restrict__ scsh,
                             unsigned short* __restrict__ Xb){
    int gid = blockIdx.x*256 + threadIdx.x;
    int c = (gid & 255) >> 3;
    Xb[gid] = f2bf(fmaf(scsh[c], bf2f(Xpre[gid]), scsh[32+c]));
}

__global__ void k_tobf16(const float* __restrict__ a, unsigned short* __restrict__ b){
    int gid = blockIdx.x*256 + threadIdx.x;
    b[gid] = f2bf(a[gid]);
}

// ---------------- effective weights (transposed, bf16) ----------------
// term: 0:W00+W10-W02-W12 1:W01 2:W11 3:2*W02 4:2*W12

__device__ __forceinline__ float weff_val(const float* W, int term, size_t base){
    const size_t S = 512*256;
    if(term==0)      return W[0*S+base] + W[3*S+base] - W[2*S+base] - W[5*S+base];
    else if(term==1) return W[1*S+base];
    else if(term==2) return W[4*S+base];
    else if(term==3) return 2.0f*W[2*S+base];
    else             return 2.0f*W[5*S+base];
}

__global__ void k_weff_zr_t(const float* __restrict__ Wz, const float* __restrict__ Wr,
                            unsigned short* __restrict__ Wt){
    int k = blockIdx.x*256 + threadIdx.x;
    int col = blockIdx.y;
    const float* W = (col < 256) ? Wz : Wr;
    int j = col & 255;
    int kb = k >> 8, rr = k & 255;
    size_t base = (size_t)((kb & 1)*256 + rr)*256 + j;
    Wt[(size_t)col*2560 + k] = f2bf(weff_val(W, kb>>1, base));
}

__global__ void k_weff_h_t(const float* __restrict__ Wh, unsigned short* __restrict__ Wt){
    int k = blockIdx.x*256 + threadIdx.x;
    int col = blockIdx.y;
    int kb = k >> 8, rr = k & 255;
    size_t base = (size_t)((kb & 1)*256 + rr)*256 + col;
    Wt[(size_t)col*2560 + k] = f2bf(weff_val(Wh, kb>>1, base));
}

// ---------------- propagation (bf16 gather via CSR, 2-edge unroll) ----------------

template<int NB, bool SAME>
__device__ __forceinline__ void acc_edge(const unsigned short* const* yo,
        const unsigned short* const* yi, size_t off, float w,
        float (*ao)[4], float (*ai)[4]){
    #pragma unroll
    for(int b=0;b<NB;b++){
        uint2 uo = *(const uint2*)(yo[b] + off);
        float fo0 = __uint_as_float(uo.x << 16), fo1 = __uint_as_float(uo.x & 0xffff0000u);
        float fo2 = __uint_as_float(uo.y << 16), fo3 = __uint_as_float(uo.y & 0xffff0000u);
        float fi0, fi1, fi2, fi3;
        if(SAME){ fi0=fo0; fi1=fo1; fi2=fo2; fi3=fo3; }
        else{
            uint2 ui = *(const uint2*)(yi[b] + off);
            fi0 = __uint_as_float(ui.x << 16); fi1 = __uint_as_float(ui.x & 0xffff0000u);
            fi2 = __uint_as_float(ui.y << 16); fi3 = __uint_as_float(ui.y & 0xffff0000u);
        }
        ao[b][0] = fmaf(w, fo0, ao[b][0]); ao[b][1] = fmaf(w, fo1, ao[b][1]);
        ao[b][2] = fmaf(w, fo2, ao[b][2]); ao[b][3] = fmaf(w, fo3, ao[b][3]);
        ai[b][0] += fi0; ai[b][1] += fi1; ai[b][2] += fi2; ai[b][3] += fi3;
    }
}

template<int NB, bool SAME>
__global__ void __launch_bounds__(256) k_prop(PPB a,
        const int* __restrict__ coloff, const int* __restrict__ esrc,
        const float* __restrict__ enormo, const float* __restrict__ invdegin){
    int node = blockIdx.x*4 + (threadIdx.x>>6);
    if(node >= NN) return;
    int lane = threadIdx.x & 63;
    int s = coloff[node], e = coloff[node+1];
    float ao[NB][4], ai[NB][4];
    #pragma unroll
    for(int b=0;b<NB;b++){
        #pragma unroll
        for(int q=0;q<4;q++){ ao[b][q]=0.f; ai[b][q]=0.f; }
    }
    const unsigned short* yo[2] = {a.yo0, a.yo1};
    const unsigned short* yi[2] = {a.yi0, a.yi1};
    int j = s;
    for(; j+1 < e; j += 2){
        int s0 = esrc[j], s1 = esrc[j+1];
        float w0 = enormo[j], w1 = enormo[j+1];
        size_t off0 = (size_t)s0*256 + lane*4;
        size_t off1 = (size_t)s1*256 + lane*4;
        acc_edge<NB,SAME>(yo, yi, off0, w0, ao, ai);
        acc_edge<NB,SAME>(yo, yi, off1, w1, ao, ai);
    }
    if(j < e){
        size_t off = (size_t)esrc[j]*256 + lane*4;
        acc_edge<NB,SAME>(yo, yi, off, enormo[j], ao, ai);
    }
    float wi = invdegin[node];
    unsigned short* po[2] = {a.po0, a.po1};
    unsigned short* pi[2] = {a.pi0, a.pi1};
    size_t oo = (size_t)node*256 + lane*4;
    #pragma unroll
    for(int b=0;b<NB;b++){
        uint2 o, q;
        o.x = ((unsigned)f2bf(ao[b][1])<<16) | f2bf(ao[b][0]);
        o.y = ((unsigned)f2bf(ao[b][3])<<16) | f2bf(ao[b][2]);
        q.x = ((unsigned)f2bf(wi*ai[b][1])<<16) | f2bf(wi*ai[b][0]);
        q.y = ((unsigned)f2bf(wi*ai[b][3])<<16) | f2bf(wi*ai[b][2]);
        *(uint2*)(po[b] + oo) = o;
        *(uint2*)(pi[b] + oo) = q;
    }
}

// ---------------- bf16 MFMA GEMM + fused GRU epilogue ----------------

template<int MODE>
__global__ void __launch_bounds__(256) k_gemm(KB10 blocks, const unsigned short* __restrict__ Wt,
        const float* __restrict__ bias0, const float* __restrict__ bias1,
        const float* __restrict__ h0, const float* __restrict__ Zin,
        float* __restrict__ out0, unsigned short* __restrict__ out1){
    __shared__ unsigned short As[4096];
    __shared__ unsigned short Bs[4096];
    int t = threadIdx.x;
    int wid = t >> 6, lane = t & 63;
    int l15 = lane & 15, kg = lane >> 4;
    int row0 = blockIdx.y * 128;
    int col0 = blockIdx.x * 128;
    int rowbase = (wid >> 1) * 64, colbase = (wid & 1) * 64;
    int swz = (l15 >> 1) & 3;
    f32x4 acc[4][4] = {};

    int c0 = t, c1 = t + 256;
    int sr0 = c0 >> 2, sg0 = (c0 & 3) ^ ((sr0 >> 1) & 3);
    int sr1 = c1 >> 2, sg1 = (c1 & 3) ^ ((sr1 >> 1) & 3);
    int gra0 = row0 + sr0; gra0 = (gra0 < NN) ? gra0 : NN-1;
    int gra1 = row0 + sr1; gra1 = (gra1 < NN) ? gra1 : NN-1;

    for(int kb=0; kb<10; kb++){
        const unsigned short* Ap = blocks.p[kb];
        const unsigned short* Wp = Wt + (size_t)kb*256;
        for(int kt=0; kt<256; kt+=32){
            gl16(Ap + (size_t)gra0*256 + kt + sg0*8, As + c0*8);
            gl16(Ap + (size_t)gra1*256 + kt + sg1*8, As + c1*8);
            gl16(Wp + (size_t)(col0+sr0)*2560 + kt + sg0*8, Bs + c0*8);
            gl16(Wp + (size_t)(col0+sr1)*2560 + kt + sg1*8, Bs + c1*8);
            __syncthreads();
            s16x8 af[4], bf[4];
            #pragma unroll
            for(int i=0;i<4;i++){
                int row = rowbase + i*16 + l15;
                af[i] = *(const s16x8*)&As[(row*4 + (kg ^ swz))*8];
                int col = colbase + i*16 + l15;
                bf[i] = *(const s16x8*)&Bs[(col*4 + (kg ^ swz))*8];
            }
            #pragma unroll
            for(int mi=0;mi<4;mi++){
                #pragma unroll
                for(int ni=0;ni<4;ni++){
                    acc[mi][ni] = __builtin_amdgcn_mfma_f32_16x16x32_bf16(
                        af[mi], bf[ni], acc[mi][ni], 0, 0, 0);
                }
            }
            __syncthreads();
        }
    }

    #pragma unroll
    for(int mi=0;mi<4;mi++){
        int gr0 = row0 + rowbase + mi*16 + kg*4;
        #pragma unroll
        for(int ni=0;ni<4;ni++){
            int j = col0 + colbase + ni*16 + l15;
            #pragma unroll
            for(int r=0;r<4;r++){
                int gr = gr0 + r;
                if(gr < NN){
                    float a = acc[mi][ni][r];
                    if(MODE == 0){
                        if(j < 256){
                            out0[(size_t)gr*256 + j] = 1.0f/(1.0f + expf(-(a + bias0[j])));
                        }else{
                            int jj = j - 256;
                            float rv = 1.0f/(1.0f + expf(-(a + bias1[jj])));
                            out1[(size_t)gr*256 + jj] = f2bf(rv * h0[(size_t)gr*256 + jj]);
                        }
                    }else{
                        float z = Zin[(size_t)gr*256 + j];
                        float ht = tanhf(a + bias0[j]);
                        float H = z*h0[(size_t)gr*256 + j] + (1.0f - z)*ht;
                        out0[(size_t)gr*256 + j] = fmaxf(H, 0.0f);
                    }
                }
            }
        }
    }
}

// ---------------- host ----------------

extern "C" void kernel_launch(void* const* d_in, const int* in_sizes, int n_in,
                              void* d_out, int out_size, void* d_ws, size_t ws_size,
                              hipStream_t stream){
    const float* x   = (const float*)d_in[0];
    const int*   ei  = (const int*)  d_in[1];
    const float* h0  = (const float*)d_in[2];
    const float* w1  = (const float*)d_in[3];
    const float* b1  = (const float*)d_in[4];
    const float* g1  = (const float*)d_in[5];
    const float* be1 = (const float*)d_in[6];
    const float* w2  = (const float*)d_in[7];
    const float* b2  = (const float*)d_in[8];
    const float* g2  = (const float*)d_in[9];
    const float* be2 = (const float*)d_in[10];
    const float* Wz  = (const float*)d_in[11];
    const float* bz  = (const float*)d_in[12];
    const float* Wr  = (const float*)d_in[13];
    const float* br  = (const float*)d_in[14];
    const float* Wh  = (const float*)d_in[15];
    const float* bh  = (const float*)d_in[16];
    float* out = (float*)d_out;
    float* wsf = (float*)d_ws;
    (void)in_sizes; (void)n_in; (void)out_size;

    const size_t O_DEGO=0, O_DEGI=20000, O_CNT=40000, O_BN=60000;      // zero: 60256
    const size_t O_COLOFF=60288, O_ESRC=80384, O_ENORMO=400384, O_INVDEG=720384;
    const size_t O_WTZR=740480, O_WTH=1395840;
    const size_t O_XF=1723520;
    const size_t O_XB=6843520, O_H0B=9403520;
    const size_t O_T1OX=11963520, O_T1IX=14523520, O_P2OX=17083520, O_P2IX=19643520;
    const size_t O_HS0=22203520, O_HS1=24763520, O_HS2=27323520, O_HS3=29883520;
    const size_t O_RH=32443520, O_Z=35003520;
    const size_t WS_NEED_BYTES = (size_t)40123520 * 4;
    if(ws_size < WS_NEED_BYTES) return;

    int* degout = (int*)(wsf + O_DEGO);
    int* degin  = (int*)(wsf + O_DEGI);
    int* cnt    = (int*)(wsf + O_CNT);
    float* bn   = wsf + O_BN;
    int* coloff = (int*)(wsf + O_COLOFF);
    int* esrc   = (int*)(wsf + O_ESRC);
    float* enormo = wsf + O_ENORMO;
    float* invdeg = wsf + O_INVDEG;
    unsigned short* Wtzr = (unsigned short*)(wsf + O_WTZR);
    unsigned short* Wth  = (unsigned short*)(wsf + O_WTH);
    unsigned short* Xpre = (unsigned short*)(wsf + O_XF);
    unsigned short* Xb   = (unsigned short*)(wsf + O_XB);
    unsigned short* h0b  = (unsigned short*)(wsf + O_H0B);
    unsigned short* T1oX = (unsigned short*)(wsf + O_T1OX);
    unsigned short* T1iX = (unsigned short*)(wsf + O_T1IX);
    unsigned short* P2oX = (unsigned short*)(wsf + O_P2OX);
    unsigned short* P2iX = (unsigned short*)(wsf + O_P2IX);
    unsigned short* HS0  = (unsigned short*)(wsf + O_HS0);
    unsigned short* HS1  = (unsigned short*)(wsf + O_HS1);
    unsigned short* HS2  = (unsigned short*)(wsf + O_HS2);
    unsigned short* HS3  = (unsigned short*)(wsf + O_HS3);
    unsigned short* RH   = (unsigned short*)(wsf + O_RH);
    float* Z = wsf + O_Z;
    unsigned short* y1b = (unsigned short*)(wsf + O_T1OX);  // 10.24M words, dead during CNN

    // graph CSR
    k_zero<<<236,256,0,stream>>>((uint32_t*)(wsf + O_DEGO), 60256);
    k_degree<<<1250,256,0,stream>>>(ei, degout, degin);
    k_scan<<<1,1024,0,stream>>>(degin, coloff, invdeg);
    k_csr<<<1250,256,0,stream>>>(ei, degout, coloff, cnt, esrc, enormo);

    // CNN embedding
    k_conv1<<<2422,256,0,stream>>>(x, w1, b1, y1b);
    k_chanstats_bf<1024,32><<<256,256,0,stream>>>(y1b, bn+0);
    k_bnfin<<<1,32,0,stream>>>(bn+0, g1, be1, bn+64, 1.0f/620000.0f);
    k_conv2<<<2500,256,0,stream>>>(y1b, w2, b2, bn+64, Xpre);
    k_chanstats_bf<256,8><<<64,256,0,stream>>>(Xpre, bn+128);
    k_bnfin<<<1,32,0,stream>>>(bn+128, g2, be2, bn+192, 1.0f/160000.0f);
    k_bnapply_bf<<<20000,256,0,stream>>>(Xpre, bn+192, Xb);
    k_tobf16<<<20000,256,0,stream>>>(h0, h0b);

    // effective weights (transposed bf16)
    k_weff_zr_t<<<dim3(10,512),256,0,stream>>>(Wz, Wr, Wtzr);
    k_weff_h_t<<<dim3(10,256),256,0,stream>>>(Wh, Wth);

    // hop1: props of X and H0
    PPB p1; p1.yo0=Xb; p1.yo1=h0b; p1.yi0=Xb; p1.yi1=h0b;
    p1.po0=T1oX; p1.po1=HS0; p1.pi0=T1iX; p1.pi1=HS1;
    k_prop<2,true><<<5000,256,0,stream>>>(p1, coloff, esrc, enormo, invdeg);

    // hop2
    PPB p2; p2.yo0=T1oX; p2.yo1=HS0; p2.yi0=T1iX; p2.yi1=HS1;
    p2.po0=P2oX; p2.po1=HS2; p2.pi0=P2iX; p2.pi1=HS3;
    k_prop<2,false><<<5000,256,0,stream>>>(p2, coloff, esrc, enormo, invdeg);

    // Z,R GEMM (fused sigmoid; RH = bf16(sigmoid(r)*h0))
    KB10 bzr = {{ Xb, h0b, T1oX, HS0, T1iX, HS1, P2oX, HS2, P2iX, HS3 }};
    k_gemm<0><<<dim3(4,157),256,0,stream>>>(bzr, Wtzr, bz, br, h0, nullptr, Z, RH);

    // props of RH (reuse dead H-side buffers)
    PPB q1; q1.yo0=RH; q1.yo1=nullptr; q1.yi0=RH; q1.yi1=nullptr;
    q1.po0=HS0; q1.po1=nullptr; q1.pi0=HS1; q1.pi1=nullptr;
    k_prop<1,true><<<5000,256,0,stream>>>(q1, coloff, esrc, enormo, invdeg);
    PPB q2; q2.yo0=HS0; q2.yo1=nullptr; q2.yi0=HS1; q2.yi1=nullptr;
    q2.po0=HS2; q2.po1=nullptr; q2.pi0=HS3; q2.pi1=nullptr;
    k_prop<1,false><<<5000,256,0,stream>>>(q2, coloff, esrc, enormo, invdeg);

    // H~ GEMM (fused tanh + gate + relu -> out)
    KB10 bhh = {{ Xb, RH, T1oX, HS0, T1iX, HS1, P2oX, HS2, P2iX, HS3 }};
    k_gemm<1><<<dim3(2,157),256,0,stream>>>(bhh, Wth, bh, nullptr, h0, Z, out, nullptr);
}

// Round 5
// 769.575 us; speedup vs baseline: 2.8619x; 1.0369x over previous
//
#include <hip/hip_runtime.h>
#include <cstdint>
#include <cstddef>

#define NN 20000
#define NE 320000

typedef float f32x4 __attribute__((ext_vector_type(4)));
typedef short s16x8 __attribute__((ext_vector_type(8)));

struct KB10 { const unsigned short* p[10]; };
struct PPB { const unsigned short* yo0; const unsigned short* yo1;
             const unsigned short* yi0; const unsigned short* yi1;
             unsigned short* po0; unsigned short* po1;
             unsigned short* pi0; unsigned short* pi1; };

__device__ __forceinline__ unsigned short f2bf(float x){
    unsigned u = __float_as_uint(x);
    unsigned r = (u + 0x7fffu + ((u >> 16) & 1u)) >> 16;
    return (unsigned short)r;
}
__device__ __forceinline__ float bf2f(unsigned short s){
    return __uint_as_float(((unsigned)s) << 16);
}

__device__ __forceinline__ void gl16(const void* g, void* l){
    __builtin_amdgcn_global_load_lds((const __attribute__((address_space(1))) unsigned int*)g,
                                     (__attribute__((address_space(3))) unsigned int*)l, 16, 0, 0);
}

// ---------------- init / graph ----------------

__global__ void k_zero(uint32_t* p, int n){
    int i = blockIdx.x*256 + threadIdx.x;
    if(i < n) p[i] = 0u;
}

__global__ void k_degree(const int* __restrict__ ei, int* degout, int* degin){
    int e = blockIdx.x*256 + threadIdx.x;
    if(e < NE){
        atomicAdd(&degout[ei[e]], 1);
        atomicAdd(&degin[ei[NE+e]], 1);
    }
}

__global__ void k_scan(const int* __restrict__ degin, int* __restrict__ coloff,
                       float* __restrict__ invdegin){
    __shared__ int part[1024];
    int t = threadIdx.x;
    int base = t*20;
    int s = 0;
    for(int k=0;k<20;k++){ int i = base+k; if(i < NN) s += degin[i]; }
    part[t] = s;
    __syncthreads();
    for(int off=1; off<1024; off<<=1){
        int v = (t>=off) ? part[t-off] : 0;
        __syncthreads();
        part[t] += v;
        __syncthreads();
    }
    int run = (t>0) ? part[t-1] : 0;
    for(int k=0;k<20;k++){
        int i = base+k;
        if(i < NN){
            int d = degin[i];
            coloff[i] = run;
            run += d;
            invdegin[i] = (d>0) ? (1.0f/(float)d) : 0.0f;
        }
    }
    if(t==1023) coloff[NN] = part[1023];
}

__global__ void k_csr(const int* __restrict__ ei, const int* __restrict__ degout,
                      const int* __restrict__ coloff, int* cnt,
                      int* __restrict__ esrc, float* __restrict__ enormo){
    int e = blockIdx.x*256 + threadIdx.x;
    if(e < NE){
        int r = ei[e], c = ei[NE+e];
        int pos = coloff[c] + atomicAdd(&cnt[c], 1);
        esrc[pos] = r;
        enormo[pos] = 1.0f/(float)degout[r];
    }
}

// ---------------- CNN embedding ----------------

__global__ void k_conv1(const float* __restrict__ x, const float* __restrict__ w1,
                        const float* __restrict__ b1, unsigned short* __restrict__ y1b){
    __shared__ float w[320];
    __shared__ float bb[32];
    int t = threadIdx.x;
    for(int i=t;i<320;i+=256) w[i] = w1[i];
    if(t < 32) bb[t] = b1[t];
    __syncthreads();
    int gid = blockIdx.x*256 + t;
    if(gid >= NN*31) return;
    int node = gid/31, p = gid - node*31;
    const float* xr = x + node*100 + 3*p;
    float xv[10];
    #pragma unroll
    for(int k=0;k<10;k++) xv[k] = xr[k];
    unsigned short* yo = y1b + (size_t)node*1024 + p;
    #pragma unroll
    for(int c=0;c<32;c++){
        float a = bb[c];
        #pragma unroll
        for(int k=0;k<10;k++) a = fmaf(w[c*10+k], xv[k], a);
        yo[c*32] = f2bf(fmaxf(a, 0.0f));
    }
    if(p == 0){
        #pragma unroll
        for(int c=0;c<32;c++) y1b[(size_t)node*1024 + c*32 + 31] = 0;
    }
}

template<int SLOTS, int PPC>
__global__ void k_chanstats_bf(const unsigned short* __restrict__ y, float* __restrict__ sq){
    int tid = blockIdx.x*blockDim.x + threadIdx.x;
    int slot = tid & (SLOTS-1);
    int node0 = tid / SLOTS;
    int nstride = (gridDim.x*blockDim.x) / SLOTS;
    int c = slot / PPC;
    float s = 0.f, q = 0.f;
    for(int n=node0; n<NN; n+=nstride){
        float v = bf2f(y[(size_t)n*SLOTS + slot]);
        s += v; q = fmaf(v, v, q);
    }
    #pragma unroll
    for(int m=PPC>>1; m>0; m>>=1){
        s += __shfl_xor(s, m);
        q += __shfl_xor(q, m);
    }
    if((threadIdx.x & (PPC-1)) == 0){
        atomicAdd(&sq[c], s);
        atomicAdd(&sq[32+c], q);
    }
}

__global__ void k_bnfin(const float* __restrict__ sq, const float* __restrict__ gamma,
                        const float* __restrict__ beta, float* __restrict__ scsh,
                        float inv_count){
    int c = threadIdx.x;
    if(c < 32){
        float m = sq[c]*inv_count;
        float v = sq[32+c]*inv_count - m*m;
        float sc = gamma[c]*rsqrtf(v + 1e-5f);
        scsh[c] = sc;
        scsh[32+c] = beta[c] - m*sc;
    }
}

// conv2: 8 nodes/block, thread=(node_local, c2), register-blocked
__global__ void __launch_bounds__(256) k_conv2(const unsigned short* __restrict__ y1b,
                        const float* __restrict__ w2, const float* __restrict__ b2,
                        const float* __restrict__ scsh1, unsigned short* __restrict__ Xpre){
    __shared__ float wlds[10240];   // [c*10+k]*32 + c2
    __shared__ float hlds[8*1040];  // [nl]*1040 + c*32 + p
    int t = threadIdx.x;
    int node0 = blockIdx.x*8;
    #pragma unroll
    for(int j=0;j<40;j++){
        int idx = j*256 + t;
        int ck = idx>>5, c2 = idx&31;
        wlds[ck*32 + c2] = w2[c2*320 + ck];
    }
    #pragma unroll
    for(int j=0;j<32;j++){
        int idx = j*256 + t;
        int nl = idx>>10, i = idx&1023;
        int c = i>>5;
        hlds[nl*1040 + i] = fmaf(scsh1[c], bf2f(y1b[(size_t)(node0+nl)*1024 + i]), scsh1[32+c]);
    }
    __syncthreads();
    int nl = t>>5, c2 = t&31;
    int hbase = nl*1040;
    float acc[8];
    float b = b2[c2];
    #pragma unroll
    for(int p=0;p<8;p++) acc[p] = b;
    for(int c=0;c<32;c++){
        float wr[10];
        #pragma unroll
        for(int k=0;k<10;k++) wr[k] = wlds[(c*10+k)*32 + c2];
        float hv[32];
        #pragma unroll
        for(int q=0;q<8;q++){
            float4 v = *(const float4*)&hlds[hbase + c*32 + q*4];
            hv[q*4+0]=v.x; hv[q*4+1]=v.y; hv[q*4+2]=v.z; hv[q*4+3]=v.w;
        }
        #pragma unroll
        for(int p=0;p<8;p++){
            #pragma unroll
            for(int k=0;k<10;k++)
                acc[p] = fmaf(wr[k], hv[3*p+k], acc[p]);
        }
    }
    uint4 pk;
    pk.x = ((unsigned)f2bf(fmaxf(acc[1],0.f))<<16) | f2bf(fmaxf(acc[0],0.f));
    pk.y = ((unsigned)f2bf(fmaxf(acc[3],0.f))<<16) | f2bf(fmaxf(acc[2],0.f));
    pk.z = ((unsigned)f2bf(fmaxf(acc[5],0.f))<<16) | f2bf(fmaxf(acc[4],0.f));
    pk.w = ((unsigned)f2bf(fmaxf(acc[7],0.f))<<16) | f2bf(fmaxf(acc[6],0.f));
    *(uint4*)&Xpre[(size_t)(node0+nl)*256 + c2*8] = pk;
}

// fused: Xb = bf16(BN2(Xpre)); h0b = bf16(h0)
__global__ void k_prep(const unsigned short* __restrict__ Xpre, const float* __restrict__ scsh,
                       const float* __restrict__ h0, unsigned short* __restrict__ Xb,
                       unsigned short* __restrict__ h0b){
    int gid = blockIdx.x*256 + threadIdx.x;
    int c = (gid & 255) >> 3;
    Xb[gid] = f2bf(fmaf(scsh[c], bf2f(Xpre[gid]), scsh[32+c]));
    h0b[gid] = f2bf(h0[gid]);
}

// ---------------- effective weights (transposed, bf16) ----------------
// term: 0:W00+W10-W02-W12 1:W01 2:W11 3:2*W02 4:2*W12

__device__ __forceinline__ float weff_val(const float* W, int term, size_t base){
    const size_t S = 512*256;
    if(term==0)      return W[0*S+base] + W[3*S+base] - W[2*S+base] - W[5*S+base];
    else if(term==1) return W[1*S+base];
    else if(term==2) return W[4*S+base];
    else if(term==3) return 2.0f*W[2*S+base];
    else             return 2.0f*W[5*S+base];
}

__global__ void k_weff_zr_t(const float* __restrict__ Wz, const float* __restrict__ Wr,
                            unsigned short* __restrict__ Wt){
    int k = blockIdx.x*256 + threadIdx.x;
    int col = blockIdx.y;
    const float* W = (col < 256) ? Wz : Wr;
    int j = col & 255;
    int kb = k >> 8, rr = k & 255;
    size_t base = (size_t)((kb & 1)*256 + rr)*256 + j;
    Wt[(size_t)col*2560 + k] = f2bf(weff_val(W, kb>>1, base));
}

__global__ void k_weff_h_t(const float* __restrict__ Wh, unsigned short* __restrict__ Wt){
    int k = blockIdx.x*256 + threadIdx.x;
    int col = blockIdx.y;
    int kb = k >> 8, rr = k & 255;
    size_t base = (size_t)((kb & 1)*256 + rr)*256 + col;
    Wt[(size_t)col*2560 + k] = f2bf(weff_val(Wh, kb>>1, base));
}

// ---------------- propagation (bf16 gather via CSR, 4-edge unroll) ----------------

__device__ __forceinline__ void upd(uint2 u, float w, float* ao4, float* ai4){
    float f0 = __uint_as_float(u.x << 16), f1 = __uint_as_float(u.x & 0xffff0000u);
    float f2 = __uint_as_float(u.y << 16), f3 = __uint_as_float(u.y & 0xffff0000u);
    ao4[0] = fmaf(w, f0, ao4[0]); ao4[1] = fmaf(w, f1, ao4[1]);
    ao4[2] = fmaf(w, f2, ao4[2]); ao4[3] = fmaf(w, f3, ao4[3]);
    ai4[0] += f0; ai4[1] += f1; ai4[2] += f2; ai4[3] += f3;
}
__device__ __forceinline__ void upd2(uint2 uo, uint2 ui, float w, float* ao4, float* ai4){
    float o0 = __uint_as_float(uo.x << 16), o1 = __uint_as_float(uo.x & 0xffff0000u);
    float o2 = __uint_as_float(uo.y << 16), o3 = __uint_as_float(uo.y & 0xffff0000u);
    float i0 = __uint_as_float(ui.x << 16), i1 = __uint_as_float(ui.x & 0xffff0000u);
    float i2 = __uint_as_float(ui.y << 16), i3 = __uint_as_float(ui.y & 0xffff0000u);
    ao4[0] = fmaf(w, o0, ao4[0]); ao4[1] = fmaf(w, o1, ao4[1]);
    ao4[2] = fmaf(w, o2, ao4[2]); ao4[3] = fmaf(w, o3, ao4[3]);
    ai4[0] += i0; ai4[1] += i1; ai4[2] += i2; ai4[3] += i3;
}

template<int NB, bool SAME>
__global__ void __launch_bounds__(256) k_prop(PPB a,
        const int* __restrict__ coloff, const int* __restrict__ esrc,
        const float* __restrict__ enormo, const float* __restrict__ invdegin){
    int node = blockIdx.x*4 + (threadIdx.x>>6);
    if(node >= NN) return;
    int lane = threadIdx.x & 63;
    int s = coloff[node], e = coloff[node+1];
    float ao[NB][4], ai[NB][4];
    #pragma unroll
    for(int b=0;b<NB;b++){
        #pragma unroll
        for(int q=0;q<4;q++){ ao[b][q]=0.f; ai[b][q]=0.f; }
    }
    const unsigned short* yo[2] = {a.yo0, a.yo1};
    const unsigned short* yi[2] = {a.yi0, a.yi1};
    int j = s;
    for(; j+3 < e; j += 4){
        int e0=esrc[j], e1=esrc[j+1], e2=esrc[j+2], e3=esrc[j+3];
        float w0=enormo[j], w1=enormo[j+1], w2=enormo[j+2], w3=enormo[j+3];
        size_t o0=(size_t)e0*256+lane*4, o1=(size_t)e1*256+lane*4;
        size_t o2=(size_t)e2*256+lane*4, o3=(size_t)e3*256+lane*4;
        uint2 A0[NB], A1[NB], A2[NB], A3[NB];
        #pragma unroll
        for(int b=0;b<NB;b++){
            A0[b]=*(const uint2*)(yo[b]+o0); A1[b]=*(const uint2*)(yo[b]+o1);
            A2[b]=*(const uint2*)(yo[b]+o2); A3[b]=*(const uint2*)(yo[b]+o3);
        }
        if(SAME){
            #pragma unroll
            for(int b=0;b<NB;b++){
                upd(A0[b], w0, ao[b], ai[b]); upd(A1[b], w1, ao[b], ai[b]);
                upd(A2[b], w2, ao[b], ai[b]); upd(A3[b], w3, ao[b], ai[b]);
            }
        }else{
            uint2 B0[NB], B1[NB], B2[NB], B3[NB];
            #pragma unroll
            for(int b=0;b<NB;b++){
                B0[b]=*(const uint2*)(yi[b]+o0); B1[b]=*(const uint2*)(yi[b]+o1);
                B2[b]=*(const uint2*)(yi[b]+o2); B3[b]=*(const uint2*)(yi[b]+o3);
            }
            #pragma unroll
            for(int b=0;b<NB;b++){
                upd2(A0[b], B0[b], w0, ao[b], ai[b]); upd2(A1[b], B1[b], w1, ao[b], ai[b]);
                upd2(A2[b], B2[b], w2, ao[b], ai[b]); upd2(A3[b], B3[b], w3, ao[b], ai[b]);
            }
        }
    }
    for(; j < e; j++){
        size_t off = (size_t)esrc[j]*256 + lane*4;
        float w = enormo[j];
        #pragma unroll
        for(int b=0;b<NB;b++){
            uint2 uo = *(const uint2*)(yo[b] + off);
            if(SAME) upd(uo, w, ao[b], ai[b]);
            else{
                uint2 ui = *(const uint2*)(yi[b] + off);
                upd2(uo, ui, w, ao[b], ai[b]);
            }
        }
    }
    float wi = invdegin[node];
    unsigned short* po[2] = {a.po0, a.po1};
    unsigned short* pi[2] = {a.pi0, a.pi1};
    size_t oo = (size_t)node*256 + lane*4;
    #pragma unroll
    for(int b=0;b<NB;b++){
        uint2 o, q;
        o.x = ((unsigned)f2bf(ao[b][1])<<16) | f2bf(ao[b][0]);
        o.y = ((unsigned)f2bf(ao[b][3])<<16) | f2bf(ao[b][2]);
        q.x = ((unsigned)f2bf(wi*ai[b][1])<<16) | f2bf(wi*ai[b][0]);
        q.y = ((unsigned)f2bf(wi*ai[b][3])<<16) | f2bf(wi*ai[b][2]);
        *(uint2*)(po[b] + oo) = o;
        *(uint2*)(pi[b] + oo) = q;
    }
}

// ---------------- bf16 MFMA GEMM, BK=64, XCD-affinity, fused GRU epilogue ----------------
// Block mapping: bid -> xcd=bid&7, s=bid>>3, cidx=s&3, r=(s>>2)*8+xcd
// (all 4 col-tiles of a row-tile land on the same XCD consecutively -> A L2 reuse)
// LDS swizzle: chunk(row, slot) = row*8 + (slot ^ (row&7)), 8 slots of 8 bf16 per 64-K row.

template<int MODE, int BNT>
__global__ void __launch_bounds__(256) k_gemm(KB10 blocks, const unsigned short* __restrict__ Wt,
        const float* __restrict__ bias0, const float* __restrict__ bias1,
        const float* __restrict__ h0, const float* __restrict__ Zin,
        float* __restrict__ out0, unsigned short* __restrict__ out1){
    constexpr int WN = BNT/32;          // fragments per wave in N
    constexpr int NBCH = BNT*8/256;     // B staging issues per thread
    __shared__ unsigned short As[128*64];
    __shared__ unsigned short Bs[BNT*64];
    int t = threadIdx.x;
    int wid = t >> 6, lane = t & 63;
    int l15 = lane & 15, kg = lane >> 4;

    int bid = blockIdx.x;
    int xcd = bid & 7, sblk = bid >> 3;
    int cidx = sblk & 3, r = (sblk >> 2)*8 + xcd;
    if(r >= 157) return;
    int row0 = r*128, col0 = cidx*BNT;
    int rowbase = (wid >> 1)*64, colbase = (wid & 1)*(BNT/2);

    // staging decode
    int rcA[4], sgA[4], graA[4];
    #pragma unroll
    for(int i=0;i<4;i++){
        int c = t + i*256;
        rcA[i] = c >> 3;
        sgA[i] = (c & 7) ^ (rcA[i] & 7);
        int gr = row0 + rcA[i];
        graA[i] = (gr < NN) ? gr : NN-1;
    }

    f32x4 acc[4][WN] = {};

    for(int kb=0; kb<10; kb++){
        const unsigned short* Ap = blocks.p[kb];
        const unsigned short* Wp = Wt + (size_t)kb*256;
        for(int kt=0; kt<256; kt+=64){
            #pragma unroll
            for(int i=0;i<4;i++)
                gl16(Ap + (size_t)graA[i]*256 + kt + sgA[i]*8, As + (t+i*256)*8);
            #pragma unroll
            for(int i=0;i<NBCH;i++)
                gl16(Wp + (size_t)(col0+rcA[i])*2560 + kt + sgA[i]*8, Bs + (t+i*256)*8);
            __syncthreads();
            #pragma unroll
            for(int ks=0;ks<2;ks++){
                s16x8 af[4], bfr[WN];
                #pragma unroll
                for(int i=0;i<4;i++){
                    int row = rowbase + i*16 + l15;
                    af[i] = *(const s16x8*)&As[(row*8 + ((ks*4+kg) ^ (row&7)))*8];
                }
                #pragma unroll
                for(int n=0;n<WN;n++){
                    int colr = colbase + n*16 + l15;
                    bfr[n] = *(const s16x8*)&Bs[(colr*8 + ((ks*4+kg) ^ (colr&7)))*8];
                }
                #pragma unroll
                for(int mi=0;mi<4;mi++){
                    #pragma unroll
                    for(int ni=0;ni<WN;ni++){
                        acc[mi][ni] = __builtin_amdgcn_mfma_f32_16x16x32_bf16(
                            af[mi], bfr[ni], acc[mi][ni], 0, 0, 0);
                    }
                }
            }
            __syncthreads();
        }
    }

    #pragma unroll
    for(int mi=0;mi<4;mi++){
        int gr0 = row0 + rowbase + mi*16 + kg*4;
        #pragma unroll
        for(int ni=0;ni<WN;ni++){
            int j = col0 + colbase + ni*16 + l15;
            #pragma unroll
            for(int rr=0;rr<4;rr++){
                int gr = gr0 + rr;
                if(gr < NN){
                    float a = acc[mi][ni][rr];
                    if(MODE == 0){
                        if(j < 256){
                            out0[(size_t)gr*256 + j] = 1.0f/(1.0f + expf(-(a + bias0[j])));
                        }else{
                            int jj = j - 256;
                            float rv = 1.0f/(1.0f + expf(-(a + bias1[jj])));
                            out1[(size_t)gr*256 + jj] = f2bf(rv * h0[(size_t)gr*256 + jj]);
                        }
                    }else{
                        float z = Zin[(size_t)gr*256 + j];
                        float ht = tanhf(a + bias0[j]);
                        float H = z*h0[(size_t)gr*256 + j] + (1.0f - z)*ht;
                        out0[(size_t)gr*256 + j] = fmaxf(H, 0.0f);
                    }
                }
            }
        }
    }
}

// ---------------- host ----------------

extern "C" void kernel_launch(void* const* d_in, const int* in_sizes, int n_in,
                              void* d_out, int out_size, void* d_ws, size_t ws_size,
                              hipStream_t stream){
    const float* x   = (const float*)d_in[0];
    const int*   ei  = (const int*)  d_in[1];
    const float* h0  = (const float*)d_in[2];
    const float* w1  = (const float*)d_in[3];
    const float* b1  = (const float*)d_in[4];
    const float* g1  = (const float*)d_in[5];
    const float* be1 = (const float*)d_in[6];
    const float* w2  = (const float*)d_in[7];
    const float* b2  = (const float*)d_in[8];
    const float* g2  = (const float*)d_in[9];
    const float* be2 = (const float*)d_in[10];
    const float* Wz  = (const float*)d_in[11];
    const float* bz  = (const float*)d_in[12];
    const float* Wr  = (const float*)d_in[13];
    const float* br  = (const float*)d_in[14];
    const float* Wh  = (const float*)d_in[15];
    const float* bh  = (const float*)d_in[16];
    float* out = (float*)d_out;
    float* wsf = (float*)d_ws;
    (void)in_sizes; (void)n_in; (void)out_size;

    const size_t O_DEGO=0, O_DEGI=20000, O_CNT=40000, O_BN=60000;      // zero: 60256
    const size_t O_COLOFF=60288, O_ESRC=80384, O_ENORMO=400384, O_INVDEG=720384;
    const size_t O_WTZR=740480, O_WTH=1395840;
    const size_t O_XF=1723520;
    const size_t O_XB=6843520, O_H0B=9403520;
    const size_t O_T1OX=11963520, O_T1IX=14523520, O_P2OX=17083520, O_P2IX=19643520;
    const size_t O_HS0=22203520, O_HS1=24763520, O_HS2=27323520, O_HS3=29883520;
    const size_t O_RH=32443520, O_Z=35003520;
    const size_t WS_NEED_BYTES = (size_t)40123520 * 4;
    if(ws_size < WS_NEED_BYTES) return;

    int* degout = (int*)(wsf + O_DEGO);
    int* degin  = (int*)(wsf + O_DEGI);
    int* cnt    = (int*)(wsf + O_CNT);
    float* bn   = wsf + O_BN;
    int* coloff = (int*)(wsf + O_COLOFF);
    int* esrc   = (int*)(wsf + O_ESRC);
    float* enormo = wsf + O_ENORMO;
    float* invdeg = wsf + O_INVDEG;
    unsigned short* Wtzr = (unsigned short*)(wsf + O_WTZR);
    unsigned short* Wth  = (unsigned short*)(wsf + O_WTH);
    unsigned short* Xpre = (unsigned short*)(wsf + O_XF);
    unsigned short* Xb   = (unsigned short*)(wsf + O_XB);
    unsigned short* h0b  = (unsigned short*)(wsf + O_H0B);
    unsigned short* T1oX = (unsigned short*)(wsf + O_T1OX);
    unsigned short* T1iX = (unsigned short*)(wsf + O_T1IX);
    unsigned short* P2oX = (unsigned short*)(wsf + O_P2OX);
    unsigned short* P2iX = (unsigned short*)(wsf + O_P2IX);
    unsigned short* HS0  = (unsigned short*)(wsf + O_HS0);
    unsigned short* HS1  = (unsigned short*)(wsf + O_HS1);
    unsigned short* HS2  = (unsigned short*)(wsf + O_HS2);
    unsigned short* HS3  = (unsigned short*)(wsf + O_HS3);
    unsigned short* RH   = (unsigned short*)(wsf + O_RH);
    float* Z = wsf + O_Z;
    unsigned short* y1b = (unsigned short*)(wsf + O_T1OX);  // dead during CNN

    // graph CSR
    k_zero<<<236,256,0,stream>>>((uint32_t*)(wsf + O_DEGO), 60256);
    k_degree<<<1250,256,0,stream>>>(ei, degout, degin);
    k_scan<<<1,1024,0,stream>>>(degin, coloff, invdeg);
    k_csr<<<1250,256,0,stream>>>(ei, degout, coloff, cnt, esrc, enormo);

    // CNN embedding
    k_conv1<<<2422,256,0,stream>>>(x, w1, b1, y1b);
    k_chanstats_bf<1024,32><<<256,256,0,stream>>>(y1b, bn+0);
    k_bnfin<<<1,32,0,stream>>>(bn+0, g1, be1, bn+64, 1.0f/620000.0f);
    k_conv2<<<2500,256,0,stream>>>(y1b, w2, b2, bn+64, Xpre);
    k_chanstats_bf<256,8><<<64,256,0,stream>>>(Xpre, bn+128);
    k_bnfin<<<1,32,0,stream>>>(bn+128, g2, be2, bn+192, 1.0f/160000.0f);
    k_prep<<<20000,256,0,stream>>>(Xpre, bn+192, h0, Xb, h0b);

    // effective weights (transposed bf16)
    k_weff_zr_t<<<dim3(10,512),256,0,stream>>>(Wz, Wr, Wtzr);
    k_weff_h_t<<<dim3(10,256),256,0,stream>>>(Wh, Wth);

    // hop1: props of X and H0
    PPB p1; p1.yo0=Xb; p1.yo1=h0b; p1.yi0=Xb; p1.yi1=h0b;
    p1.po0=T1oX; p1.po1=HS0; p1.pi0=T1iX; p1.pi1=HS1;
    k_prop<2,true><<<5000,256,0,stream>>>(p1, coloff, esrc, enormo, invdeg);

    // hop2
    PPB p2; p2.yo0=T1oX; p2.yo1=HS0; p2.yi0=T1iX; p2.yi1=HS1;
    p2.po0=P2oX; p2.po1=HS2; p2.pi0=P2iX; p2.pi1=HS3;
    k_prop<2,false><<<5000,256,0,stream>>>(p2, coloff, esrc, enormo, invdeg);

    // Z,R GEMM (fused sigmoid; RH = bf16(sigmoid(r)*h0))
    KB10 bzr = {{ Xb, h0b, T1oX, HS0, T1iX, HS1, P2oX, HS2, P2iX, HS3 }};
    k_gemm<0,128><<<640,256,0,stream>>>(bzr, Wtzr, bz, br, h0, nullptr, Z, RH);

    // props of RH (reuse dead H-side buffers)
    PPB q1; q1.yo0=RH; q1.yo1=nullptr; q1.yi0=RH; q1.yi1=nullptr;
    q1.po0=HS0; q1.po1=nullptr; q1.pi0=HS1; q1.pi1=nullptr;
    k_prop<1,true><<<5000,256,0,stream>>>(q1, coloff, esrc, enormo, invdeg);
    PPB q2; q2.yo0=HS0; q2.yo1=nullptr; q2.yi0=HS1; q2.yi1=nullptr;
    q2.po0=HS2; q2.po1=nullptr; q2.pi0=HS3; q2.pi1=nullptr;
    k_prop<1,false><<<5000,256,0,stream>>>(q2, coloff, esrc, enormo, invdeg);

    // H~ GEMM (fused tanh + gate + relu -> out)
    KB10 bhh = {{ Xb, RH, T1oX, HS0, T1iX, HS1, P2oX, HS2, P2iX, HS3 }};
    k_gemm<1,64><<<640,256,0,stream>>>(bhh, Wth, bh, nullptr, h0, Z, out, nullptr);
}